// Round 13
// baseline (103.187 us; speedup 1.0000x reference)
//
#include <hip/hip_runtime.h>
#include <hip/hip_bf16.h>

// R24 = in-block split-K. Two R21-verbatim 8-wave engines per 1024-thread
// block: group 0 = key tiles [0, ceil(nt/2)), group 1 = rest. Same grid 512
// (64 ranks x 8 q-slots, QT=128), private dbuf K/V LDS per group (64KB ->
// still 2 blocks/CU). Wins: (i) 32 waves/CU (8/SIMD max) vs R21's
// grid-capped 16; (ii) serial chain halved 16->8 tiles (attacks the ~14us
// drain: occupancy-time said ~44% of R21 is tail); (iii) barriers per key
// halved. Loop trip = ceil(nt/2) for ALL waves (surplus group-1 steps
// idle-but-barrier -> uniform barrier count, no deadlock). Buffer lifetime
// discipline per group identical to R21 (one barrier/step separates reads
// of buf[bs^1] from its restaging). Epilogue: group 1 stashes raw (O,m,l)
// to dead K-LDS; group 0 merges exactly (m*=max; w=exp2(m-m*);
// O=(O0w0+O1w1)/(l0w0+l1w1)) and stores. Same online-softmax math, not
// bit-identical to R21 (split changes summation grouping); margin 3.8x.

#define NB    64
#define LQ    1024
#define LK    1024
#define DH    64
#define KVT   64
#define QT    128
#define NITEMS (NB * (LQ / QT))      // 512
#define NEGF  1.0e30f
#define SC2   0.18033688011112042f   // 0.125 * log2(e)
#define THR   8.0f                   // defer-max threshold (log2 units)

typedef __attribute__((ext_vector_type(8))) short    bf8;
typedef __attribute__((ext_vector_type(8))) ushort   u16x8;
typedef __attribute__((ext_vector_type(4))) ushort   u16x4;
typedef __attribute__((ext_vector_type(4))) float    f4;

__device__ __forceinline__ ushort2 cvt2(float a, float b) {   // v_cvt_pk_bf16_f32
    float2 f; f.x = a; f.y = b;
    __hip_bfloat162 h = __float22bfloat162_rn(f);
    union { __hip_bfloat162 h2; ushort2 u2; } u;
    u.h2 = h;
    return u.u2;
}
__device__ __forceinline__ int swz16(int row, int colbyte) {  // K, V^T tiles
    return row * 128 + ((((colbyte >> 4) ^ (row & 7)) << 4) | (colbyte & 15));
}
__device__ __forceinline__ float fm3(float a, float b, float c) {  // v_max3
    return fmaxf(fmaxf(a, b), c);
}

__global__ __launch_bounds__(1024, 8)
void attn_v24(const float* __restrict__ Q, const float* __restrict__ K,
              const float* __restrict__ V, const int* __restrict__ VL,
              float* __restrict__ O) {
    __shared__ ushort KsB[2][2][KVT * DH];  // [grp][buf] swz16   32 KB
    __shared__ ushort VtB[2][2][DH * KVT];  // [grp][buf] swz16   32 KB
    __shared__ ushort sched[NB];            //                     128 B => 65664

    const int tid = threadIdx.x;
    const int wid = tid >> 6;             // 0..15
    const int grp = wid >> 3;             // key-half group 0/1
    const int gw  = wid & 7;              // wave within group (R21's wid role)
    const int l = tid & 63, g = l >> 4, a = l & 15;

    // ---- in-kernel stratified-LPT schedule ----
    if (tid < NB) {
        const int ntb = (VL[tid] + KVT - 1) >> 6;
        int r = 0;
        for (int j = 0; j < NB; ++j) {
            const int ntj = (VL[j] + KVT - 1) >> 6;
            r += (int)((ntj > ntb) | ((ntj == ntb) & (j < tid)));
        }
        sched[r] = (ushort)tid;           // rank -> batch (desc nt, tie asc)
    }
    __syncthreads();
    const int xcd   = blockIdx.x & 7;     // HW: block i -> XCD i%8
    const int slot  = blockIdx.x >> 3;    // 0..63 within XCD
    const int qtile = slot & 7;           // 8 q-slots of 128 rows
    const int st    = slot >> 3;          // stratum 0..7
    const int rank  = xcd + ((st < 4) ? st : (11 - st)) * 8;  // pairing perm
    const int b     = sched[rank];
    const int qbase = qtile * QT;
    const int valid = VL[b];              // 1..1024
    const int nt = (valid + KVT - 1) >> 6;
    const int hA   = (nt + 1) >> 1;       // group-0 tile count (loop trip)
    const int myN  = grp ? (nt - hA) : hA;
    const int tbase = grp ? hA : 0;

    // Hoisted LDS read offsets (shared by K and V reads)
    int off8[8];                          // [n][kblk] -> n*2 + kblk
    #pragma unroll
    for (int n = 0; n < 4; ++n)
        #pragma unroll
        for (int kblk = 0; kblk < 2; ++kblk)
            off8[n * 2 + kblk] = swz16(n * 16 + a, kblk * 64 + g * 16);

    // Q fragment (B-operand), pre-scaled by SC2: q-row = qbase + gw*16 + a
    const float* Qr = Q + ((size_t)b * LQ + qbase + gw * 16 + a) * DH;
    bf8 qa[2];
    #pragma unroll
    for (int kblk = 0; kblk < 2; ++kblk) {
        f4 x = *(const f4*)(Qr + kblk * 32 + g * 8);
        f4 y = *(const f4*)(Qr + kblk * 32 + g * 8 + 4);
        ushort2 c0 = cvt2(x[0] * SC2, x[1] * SC2), c1 = cvt2(x[2] * SC2, x[3] * SC2);
        ushort2 c2 = cvt2(y[0] * SC2, y[1] * SC2), c3 = cvt2(y[2] * SC2, y[3] * SC2);
        qa[kblk][0] = (short)c0.x; qa[kblk][1] = (short)c0.y;
        qa[kblk][2] = (short)c1.x; qa[kblk][3] = (short)c1.y;
        qa[kblk][4] = (short)c2.x; qa[kblk][5] = (short)c2.y;
        qa[kblk][6] = (short)c3.x; qa[kblk][7] = (short)c3.y;
    }
    const bf8 ones = {0x3F80, 0x3F80, 0x3F80, 0x3F80,
                      0x3F80, 0x3F80, 0x3F80, 0x3F80};   // bf16 1.0 x8

    // staging roles within each 512-thread group (R21 split: gw 0-3 V, 4-7 K)
    const int  ltid  = tid & 511;
    const int  rtid  = ltid & 255;
    const bool vrole = (gw < 4);
    const int srow = rtid >> 3, sslot = rtid & 7;   // K rows srow, srow+32
    const int vkp  = rtid >> 4, vj = rtid & 15;     // V keys 4vkp.., f4-col vj
    const int prow = (srow & 3) | ((srow & 24) >> 1) | ((srow & 4) << 2);
    const f4* Kb4 = (const f4*)(K + (size_t)b * LK * DH);
    const f4* Vb4 = (const f4*)(V + (size_t)b * LK * DH);
    char* kbase[2] = {(char*)&KsB[grp][0][0], (char*)&KsB[grp][1][0]};
    char* vbase[2] = {(char*)&VtB[grp][0][0], (char*)&VtB[grp][1][0]};

    f4 r0, r1, r2, r3;
    auto load_kv = [&](int k0) {
        if (vrole) {
            r0 = Vb4[(k0 + 4 * vkp + 0) * 16 + vj];
            r1 = Vb4[(k0 + 4 * vkp + 1) * 16 + vj];
            r2 = Vb4[(k0 + 4 * vkp + 2) * 16 + vj];
            r3 = Vb4[(k0 + 4 * vkp + 3) * 16 + vj];
        } else {
            r0 = Kb4[(k0 + srow) * 16 + sslot * 2];
            r1 = Kb4[(k0 + srow) * 16 + sslot * 2 + 1];
            r2 = Kb4[(k0 + srow + 32) * 16 + sslot * 2];
            r3 = Kb4[(k0 + srow + 32) * 16 + sslot * 2 + 1];
        }
    };
    auto store_kv = [&](int bs) {
        if (vrole) {
            char* vd = vbase[bs];
            #pragma unroll
            for (int c = 0; c < 4; ++c) {      // transpose: d = 4*vj+c
                ushort2 a01 = cvt2(r0[c], r1[c]), a23 = cvt2(r2[c], r3[c]);
                u16x4 p = {a01.x, a01.y, a23.x, a23.y};
                *(u16x4*)(vd + swz16(4 * vj + c, vkp * 8)) = p;
            }
        } else {
            char* kd = kbase[bs];
            {
                ushort2 c0 = cvt2(r0[0], r0[1]), c1 = cvt2(r0[2], r0[3]);
                ushort2 c2 = cvt2(r1[0], r1[1]), c3 = cvt2(r1[2], r1[3]);
                u16x8 w = {c0.x, c0.y, c1.x, c1.y, c2.x, c2.y, c3.x, c3.y};
                *(u16x8*)(kd + swz16(prow, sslot * 16)) = w;
            }
            {
                ushort2 c0 = cvt2(r2[0], r2[1]), c1 = cvt2(r2[2], r2[3]);
                ushort2 c2 = cvt2(r3[0], r3[1]), c3 = cvt2(r3[2], r3[3]);
                u16x8 w = {c0.x, c0.y, c1.x, c1.y, c2.x, c2.y, c3.x, c3.y};
                *(u16x8*)(kd + swz16(prow + 32, sslot * 16)) = w;
            }
        }
    };

    f4 oacc[4];
    #pragma unroll
    for (int n = 0; n < 4; ++n) oacc[n] = f4{0.f, 0.f, 0.f, 0.f};
    f4 lacc = f4{0.f, 0.f, 0.f, 0.f};   // l per q-row 4g+r
    float m_run = -NEGF;                // per-lane: q-row = a

    if (myN > 0) { load_kv(tbase * KVT); store_kv(0); }

    auto tile_iter = [&](int u, const int bs) {
        __syncthreads();                         // buf[bs] ready group-wide
        if (u + 1 < myN) load_kv((tbase + u + 1) * KVT);
        __builtin_amdgcn_sched_barrier(0);
        if (u < myN) {
            // ---- S^T = K Q^T (R21 body) ----
            const char* kd = kbase[bs];
            f4 sacc[4];
            #pragma unroll
            for (int n = 0; n < 4; ++n) sacc[n] = f4{0.f, 0.f, 0.f, 0.f};
            __builtin_amdgcn_s_setprio(1);
            #pragma unroll
            for (int n = 0; n < 4; ++n)
                #pragma unroll
                for (int kblk = 0; kblk < 2; ++kblk) {
                    bf8 kb = *(const bf8*)(kd + off8[n * 2 + kblk]);
                    sacc[n] = __builtin_amdgcn_mfma_f32_16x16x32_bf16(
                        kb, qa[kblk], sacc[n], 0, 0, 0);
                }
            __builtin_amdgcn_s_setprio(0);

            const int kmax = valid - (tbase + u) * KVT;
            if (kmax < KVT) {
                #pragma unroll
                for (int n = 0; n < 4; ++n)
                    #pragma unroll
                    for (int r = 0; r < 4; ++r)
                        if (32 * (n >> 1) + 4 * (n & 1) + 8 * g + r >= kmax)
                            sacc[n][r] = -NEGF;
            }

            float t0 = fm3(sacc[0][0], sacc[0][1], sacc[0][2]);
            float t1 = fm3(sacc[0][3], sacc[1][0], sacc[1][1]);
            float t2 = fm3(sacc[1][2], sacc[1][3], sacc[2][0]);
            float t3 = fm3(sacc[2][1], sacc[2][2], sacc[2][3]);
            float t4 = fm3(sacc[3][0], sacc[3][1], sacc[3][2]);
            float tm = fmaxf(fm3(t0, t1, t2), fm3(t3, t4, sacc[3][3]));
            tm = fmaxf(tm, __shfl_xor(tm, 16));
            tm = fmaxf(tm, __shfl_xor(tm, 32));

            float rs_ = 1.0f;                     // T13 defer-max
            const bool skip = __all(tm <= m_run + THR);
            if (!skip) {
                const float mnew = fmaxf(m_run, tm);
                rs_ = __builtin_exp2f(m_run - mnew);
                m_run = mnew;
            }

            float p[4][4];
            #pragma unroll
            for (int n = 0; n < 4; ++n)
                #pragma unroll
                for (int r = 0; r < 4; ++r)
                    p[n][r] = __builtin_exp2f(sacc[n][r] - m_run);

            if (!skip) {
                float rr[4];
                #pragma unroll
                for (int r = 0; r < 4; ++r) rr[r] = __shfl(rs_, 4 * g + r);
                #pragma unroll
                for (int n = 0; n < 4; ++n)
                    #pragma unroll
                    for (int r = 0; r < 4; ++r) oacc[n][r] *= rr[r];
                #pragma unroll
                for (int r = 0; r < 4; ++r) lacc[r] *= rr[r];
            }

            const char* vd = vbase[bs];
            __builtin_amdgcn_s_setprio(1);
            #pragma unroll
            for (int kblk = 0; kblk < 2; ++kblk) {
                ushort2 w0 = cvt2(p[2 * kblk][0], p[2 * kblk][1]);
                ushort2 w1 = cvt2(p[2 * kblk][2], p[2 * kblk][3]);
                ushort2 w2 = cvt2(p[2 * kblk + 1][0], p[2 * kblk + 1][1]);
                ushort2 w3 = cvt2(p[2 * kblk + 1][2], p[2 * kblk + 1][3]);
                bf8 pa = {(short)w0.x, (short)w0.y, (short)w1.x, (short)w1.y,
                          (short)w2.x, (short)w2.y, (short)w3.x, (short)w3.y};
                #pragma unroll
                for (int n = 0; n < 4; ++n) {
                    bf8 vb_ = *(const bf8*)(vd + off8[n * 2 + kblk]);
                    oacc[n] = __builtin_amdgcn_mfma_f32_16x16x32_bf16(
                        pa, vb_, oacc[n], 0, 0, 0);
                }
                lacc = __builtin_amdgcn_mfma_f32_16x16x32_bf16(pa, ones, lacc, 0, 0, 0);
            }
            __builtin_amdgcn_s_setprio(0);
        }
        if (u + 1 < myN) store_kv(bs ^ 1);
    };

    for (int u = 0; u < hA; u += 2) {       // uniform trip count, bs literal
        tile_iter(u, 0);
        if (u + 1 < hA) tile_iter(u + 1, 1);
    }

    // ---- merge: group 1 stashes raw partials; group 0 combines + stores ----
    __syncthreads();                         // all tile work + staging done
    float* Oex = (float*)&KsB[0][0][0];      // [gw][n][row16][col16]  32 KB
    float* lex = (float*)&VtB[0][0][0];      // [gw][row16]
    float* mex = lex + 128;                  // [gw][row16]
    if (grp == 1) {
        #pragma unroll
        for (int n = 0; n < 4; ++n)
            #pragma unroll
            for (int r = 0; r < 4; ++r)
                Oex[((gw * 4 + n) * 16 + (4 * g + r)) * 16 + a] = oacc[n][r];
        if (a == 0) {
            #pragma unroll
            for (int r = 0; r < 4; ++r) lex[gw * 16 + 4 * g + r] = lacc[r];
        }
        if (g == 0) mex[gw * 16 + a] = m_run;
    }
    __syncthreads();
    if (grp == 0) {
        float w0[4], w1[4], iv[4];
        #pragma unroll
        for (int r = 0; r < 4; ++r) {
            const float m0r = __shfl(m_run, 4 * g + r);
            const float m1r = mex[gw * 16 + 4 * g + r];
            const float l1r = lex[gw * 16 + 4 * g + r];
            const float mm  = fmaxf(m0r, m1r);
            w0[r] = __builtin_exp2f(m0r - mm);
            w1[r] = __builtin_exp2f(m1r - mm);
            iv[r] = 1.0f / (lacc[r] * w0[r] + l1r * w1[r]);
        }
        float* Ob = O + ((size_t)b * LQ + qbase + gw * 16) * DH;
        #pragma unroll
        for (int n = 0; n < 4; ++n)
            #pragma unroll
            for (int r = 0; r < 4; ++r) {
                const float o1 = Oex[((gw * 4 + n) * 16 + (4 * g + r)) * 16 + a];
                Ob[(size_t)(4 * g + r) * DH + 16 * n + a] =
                    (oacc[n][r] * w0[r] + o1 * w1[r]) * iv[r];
            }
    }
}

extern "C" void kernel_launch(void* const* d_in, const int* in_sizes, int n_in,
                              void* d_out, int out_size, void* d_ws, size_t ws_size,
                              hipStream_t stream) {
    const float* Q  = (const float*)d_in[0];
    const float* K  = (const float*)d_in[1];
    const float* V  = (const float*)d_in[2];
    const int*   VL = (const int*)d_in[3];
    float* O = (float*)d_out;

    attn_v24<<<NITEMS, 1024, 0, stream>>>(Q, K, V, VL, O);
}

// Round 14
// 33.000 us; speedup vs baseline: 3.1268x; 3.1268x over previous
//
#include <hip/hip_runtime.h>
#include <hip/hip_bf16.h>

// R25 = R21 VERBATIM (verified champion, 33.06us). Restores state after R24's
// spill catastrophe: __launch_bounds__(1024,8) forced a 64-reg unified budget,
// allocator emitted 32 arch-VGPRs + scratch spills (FETCH 17->164MB, WRITE
// 16->233MB, MfmaUtil 3.3%) -- split-K never actually ran unspilled, and its
// relaxed-bounds variant collapses to R21 residency + merge overhead. Closed.
// Structure ledger: R17 (fewer waves), R18 (2-barrier lockstep), R19 (128-key
// iters), R24 (split-K) all regressed; R20/R22/R23 micro-deltas neutral-to-
// negative. R21's loose 8-wave/16-q-row single-barrier loop with hoisted
// offsets + unroll-2 is the verified optimum of everything explored.

#define NB    64
#define LQ    1024
#define LK    1024
#define DH    64
#define KVT   64
#define QT    128
#define NITEMS (NB * (LQ / QT))      // 512
#define NEGF  1.0e30f
#define SC2   0.18033688011112042f   // 0.125 * log2(e)
#define THR   8.0f                   // defer-max threshold (log2 units)

typedef __attribute__((ext_vector_type(8))) short    bf8;
typedef __attribute__((ext_vector_type(8))) ushort   u16x8;
typedef __attribute__((ext_vector_type(4))) ushort   u16x4;
typedef __attribute__((ext_vector_type(4))) float    f4;

__device__ __forceinline__ ushort2 cvt2(float a, float b) {   // v_cvt_pk_bf16_f32
    float2 f; f.x = a; f.y = b;
    __hip_bfloat162 h = __float22bfloat162_rn(f);
    union { __hip_bfloat162 h2; ushort2 u2; } u;
    u.h2 = h;
    return u.u2;
}
__device__ __forceinline__ int swz16(int row, int colbyte) {  // K, V^T tiles
    return row * 128 + ((((colbyte >> 4) ^ (row & 7)) << 4) | (colbyte & 15));
}
__device__ __forceinline__ float fm3(float a, float b, float c) {  // v_max3
    return fmaxf(fmaxf(a, b), c);
}

__global__ __launch_bounds__(512, 4)
void attn_v25(const float* __restrict__ Q, const float* __restrict__ K,
              const float* __restrict__ V, const int* __restrict__ VL,
              float* __restrict__ O) {
    __shared__ ushort KsB[2][KVT * DH];   // swz16 [phys key][d] 16 KB
    __shared__ ushort VtB[2][DH * KVT];   // swz16 [d][key]      16 KB
    __shared__ ushort sched[NB];          // rank -> batch        128 B => 32896

    const int tid = threadIdx.x;
    const int wid = tid >> 6, l = tid & 63, g = l >> 4, a = l & 15;

    // ---- in-kernel stratified-LPT schedule ----
    if (tid < NB) {
        const int ntb = (VL[tid] + KVT - 1) >> 6;
        int r = 0;
        for (int j = 0; j < NB; ++j) {
            const int ntj = (VL[j] + KVT - 1) >> 6;
            r += (int)((ntj > ntb) | ((ntj == ntb) & (j < tid)));
        }
        sched[r] = (ushort)tid;           // rank -> batch (desc nt, tie asc)
    }
    __syncthreads();
    const int xcd   = blockIdx.x & 7;     // HW: block i -> XCD i%8
    const int slot  = blockIdx.x >> 3;    // 0..63 within XCD
    const int qtile = slot & 7;           // 8 q-slots of 128 rows
    const int st    = slot >> 3;          // stratum 0..7
    // pairing perm8={0,1,2,3,7,6,5,4}: CU gets complementary strata
    const int rank  = xcd + ((st < 4) ? st : (11 - st)) * 8;
    const int b     = sched[rank];
    const int qbase = qtile * QT;
    const int valid = VL[b];              // 1..1024
    const int nt = (valid + KVT - 1) >> 6;

    // Hoisted LDS read offsets: same formula serves K and V reads.
    int off8[8];                          // [n][kblk] -> n*2 + kblk
    #pragma unroll
    for (int n = 0; n < 4; ++n)
        #pragma unroll
        for (int kblk = 0; kblk < 2; ++kblk)
            off8[n * 2 + kblk] = swz16(n * 16 + a, kblk * 64 + g * 16);

    // Q fragment (B-operand), pre-scaled by SC2: col=a (q-row), k=32kblk+8g+i
    const float* Qr = Q + ((size_t)b * LQ + qbase + wid * 16 + a) * DH;
    bf8 qa[2];
    #pragma unroll
    for (int kblk = 0; kblk < 2; ++kblk) {
        f4 x = *(const f4*)(Qr + kblk * 32 + g * 8);
        f4 y = *(const f4*)(Qr + kblk * 32 + g * 8 + 4);
        ushort2 c0 = cvt2(x[0] * SC2, x[1] * SC2), c1 = cvt2(x[2] * SC2, x[3] * SC2);
        ushort2 c2 = cvt2(y[0] * SC2, y[1] * SC2), c3 = cvt2(y[2] * SC2, y[3] * SC2);
        qa[kblk][0] = (short)c0.x; qa[kblk][1] = (short)c0.y;
        qa[kblk][2] = (short)c1.x; qa[kblk][3] = (short)c1.y;
        qa[kblk][4] = (short)c2.x; qa[kblk][5] = (short)c2.y;
        qa[kblk][6] = (short)c3.x; qa[kblk][7] = (short)c3.y;
    }
    const bf8 ones = {0x3F80, 0x3F80, 0x3F80, 0x3F80,
                      0x3F80, 0x3F80, 0x3F80, 0x3F80};   // bf16 1.0 x8

    // staging roles: waves 0-3 stage V, waves 4-7 stage K (R16 split)
    const int  rtid  = tid & 255;
    const bool vrole = (wid < 4);
    const int srow = rtid >> 3, sslot = rtid & 7;   // K rows srow, srow+32
    const int vkp  = rtid >> 4, vj = rtid & 15;     // V keys 4vkp.., f4-col vj
    // physical LDS row for K key srow (<32): swap bits 3..4 with bit 2
    const int prow = (srow & 3) | ((srow & 24) >> 1) | ((srow & 4) << 2);
    const f4* Kb4 = (const f4*)(K + (size_t)b * LK * DH);
    const f4* Vb4 = (const f4*)(V + (size_t)b * LK * DH);

    f4 r0, r1, r2, r3;
    auto load_kv = [&](int k0) {
        if (vrole) {
            r0 = Vb4[(k0 + 4 * vkp + 0) * 16 + vj];
            r1 = Vb4[(k0 + 4 * vkp + 1) * 16 + vj];
            r2 = Vb4[(k0 + 4 * vkp + 2) * 16 + vj];
            r3 = Vb4[(k0 + 4 * vkp + 3) * 16 + vj];
        } else {
            r0 = Kb4[(k0 + srow) * 16 + sslot * 2];
            r1 = Kb4[(k0 + srow) * 16 + sslot * 2 + 1];
            r2 = Kb4[(k0 + srow + 32) * 16 + sslot * 2];
            r3 = Kb4[(k0 + srow + 32) * 16 + sslot * 2 + 1];
        }
    };
    auto store_kv = [&](int bs) {
        if (vrole) {
            char* vd = (char*)&VtB[bs][0];
            #pragma unroll
            for (int c = 0; c < 4; ++c) {      // transpose: d = 4*vj+c
                ushort2 a01 = cvt2(r0[c], r1[c]), a23 = cvt2(r2[c], r3[c]);
                u16x4 p = {a01.x, a01.y, a23.x, a23.y};
                *(u16x4*)(vd + swz16(4 * vj + c, vkp * 8)) = p;
            }
        } else {
            char* kd = (char*)&KsB[bs][0];
            {
                ushort2 c0 = cvt2(r0[0], r0[1]), c1 = cvt2(r0[2], r0[3]);
                ushort2 c2 = cvt2(r1[0], r1[1]), c3 = cvt2(r1[2], r1[3]);
                u16x8 w = {c0.x, c0.y, c1.x, c1.y, c2.x, c2.y, c3.x, c3.y};
                *(u16x8*)(kd + swz16(prow, sslot * 16)) = w;
            }
            {
                ushort2 c0 = cvt2(r2[0], r2[1]), c1 = cvt2(r2[2], r2[3]);
                ushort2 c2 = cvt2(r3[0], r3[1]), c3 = cvt2(r3[2], r3[3]);
                u16x8 w = {c0.x, c0.y, c1.x, c1.y, c2.x, c2.y, c3.x, c3.y};
                *(u16x8*)(kd + swz16(prow + 32, sslot * 16)) = w;
            }
        }
    };

    f4 oacc[4];
    #pragma unroll
    for (int n = 0; n < 4; ++n) oacc[n] = f4{0.f, 0.f, 0.f, 0.f};
    f4 lacc = f4{0.f, 0.f, 0.f, 0.f};   // l per q-row 4g+r (epilogue layout)
    float m_run = -NEGF;                // per-lane: q-row = a

    // One tile iteration; bs is a LITERAL at every callsite so the LDS base
    // folds into ds_read/ds_write immediates.
    auto tile_iter = [&](int t, const int bs) {
        __syncthreads();                         // buf[bs] ready block-wide
        if (t + 1 < nt) load_kv((t + 1) * KVT);  // issue early...
        __builtin_amdgcn_sched_barrier(0);       // ...keep it early

        // ---- S^T = K Q^T: lane (g,a) holds S[q=a][key=32(n>>1)+4(n&1)+8g+r]
        const char* kd = (const char*)&KsB[bs][0];
        f4 sacc[4];
        #pragma unroll
        for (int n = 0; n < 4; ++n) sacc[n] = f4{0.f, 0.f, 0.f, 0.f};
        __builtin_amdgcn_s_setprio(1);
        #pragma unroll
        for (int n = 0; n < 4; ++n)
            #pragma unroll
            for (int kblk = 0; kblk < 2; ++kblk) {
                bf8 kb = *(const bf8*)(kd + off8[n * 2 + kblk]);
                sacc[n] = __builtin_amdgcn_mfma_f32_16x16x32_bf16(
                    kb, qa[kblk], sacc[n], 0, 0, 0);   // A=K, B=Q
            }
        __builtin_amdgcn_s_setprio(0);

        // ---- mask in place ----
        const int kmax = valid - t * KVT;
        if (kmax < KVT) {
            #pragma unroll
            for (int n = 0; n < 4; ++n)
                #pragma unroll
                for (int r = 0; r < 4; ++r)
                    if (32 * (n >> 1) + 4 * (n & 1) + 8 * g + r >= kmax)
                        sacc[n][r] = -NEGF;
        }

        // ---- softmax max: 3-ary tree (v_max3) + 2 shfl over g ----
        float t0 = fm3(sacc[0][0], sacc[0][1], sacc[0][2]);
        float t1 = fm3(sacc[0][3], sacc[1][0], sacc[1][1]);
        float t2 = fm3(sacc[1][2], sacc[1][3], sacc[2][0]);
        float t3 = fm3(sacc[2][1], sacc[2][2], sacc[2][3]);
        float t4 = fm3(sacc[3][0], sacc[3][1], sacc[3][2]);
        float tm = fm3(fm3(t0, t1, t2), fm3(t3, t4, sacc[3][3]),
                       -NEGF);
        tm = fmaxf(tm, __shfl_xor(tm, 16));
        tm = fmaxf(tm, __shfl_xor(tm, 32));

        float rs_ = 1.0f;                     // T13 defer-max
        const bool skip = __all(tm <= m_run + THR);
        if (!skip) {
            const float mnew = fmaxf(m_run, tm);
            rs_ = __builtin_exp2f(m_run - mnew);   // tile0: exp2(-inf)=0
            m_run = mnew;
        }

        float p[4][4];
        #pragma unroll
        for (int n = 0; n < 4; ++n)
            #pragma unroll
            for (int r = 0; r < 4; ++r)
                p[n][r] = __builtin_exp2f(sacc[n][r] - m_run);   // masked -> 0

        if (!skip) {   // rescale O,l rows (q=4g+r)
            float rr[4];
            #pragma unroll
            for (int r = 0; r < 4; ++r) rr[r] = __shfl(rs_, 4 * g + r);
            #pragma unroll
            for (int n = 0; n < 4; ++n)
                #pragma unroll
                for (int r = 0; r < 4; ++r) oacc[n][r] *= rr[r];
            #pragma unroll
            for (int r = 0; r < 4; ++r) lacc[r] *= rr[r];
        }

        // ---- O += P V ; l += P * ones  (P in registers; vb one b128) ----
        const char* vd = (const char*)&VtB[bs][0];
        __builtin_amdgcn_s_setprio(1);
        #pragma unroll
        for (int kblk = 0; kblk < 2; ++kblk) {
            ushort2 w0 = cvt2(p[2 * kblk][0], p[2 * kblk][1]);
            ushort2 w1 = cvt2(p[2 * kblk][2], p[2 * kblk][3]);
            ushort2 w2 = cvt2(p[2 * kblk + 1][0], p[2 * kblk + 1][1]);
            ushort2 w3 = cvt2(p[2 * kblk + 1][2], p[2 * kblk + 1][3]);
            bf8 pa = {(short)w0.x, (short)w0.y, (short)w1.x, (short)w1.y,
                      (short)w2.x, (short)w2.y, (short)w3.x, (short)w3.y};
            #pragma unroll
            for (int n = 0; n < 4; ++n) {
                bf8 vb_ = *(const bf8*)(vd + off8[n * 2 + kblk]);
                oacc[n] = __builtin_amdgcn_mfma_f32_16x16x32_bf16(
                    pa, vb_, oacc[n], 0, 0, 0);
            }
            lacc = __builtin_amdgcn_mfma_f32_16x16x32_bf16(pa, ones, lacc, 0, 0, 0);
        }
        __builtin_amdgcn_s_setprio(0);

        if (t + 1 < nt) store_kv(bs ^ 1);   // post-compute, pre-next-barrier
    };

    load_kv(0);
    store_kv(0);
    for (int t = 0; t < nt; t += 2) {       // unroll-2: bs literal
        tile_iter(t, 0);
        if (t + 1 < nt) tile_iter(t + 1, 1);
    }

    // ---- epilogue: O[q=4g+r][d=16n+a] / l (lacc already row-layout) ----
    float iv[4];
    #pragma unroll
    for (int r = 0; r < 4; ++r) iv[r] = 1.0f / lacc[r];
    float* Ob = O + ((size_t)b * LQ + qbase + wid * 16) * DH;
    #pragma unroll
    for (int n = 0; n < 4; ++n)
        #pragma unroll
        for (int r = 0; r < 4; ++r)
            Ob[(size_t)(4 * g + r) * DH + 16 * n + a] = oacc[n][r] * iv[r];
}

extern "C" void kernel_launch(void* const* d_in, const int* in_sizes, int n_in,
                              void* d_out, int out_size, void* d_ws, size_t ws_size,
                              hipStream_t stream) {
    const float* Q  = (const float*)d_in[0];
    const float* K  = (const float*)d_in[1];
    const float* V  = (const float*)d_in[2];
    const int*   VL = (const int*)d_in[3];
    float* O = (float*)d_out;

    attn_v25<<<NITEMS, 512, 0, stream>>>(Q, K, V, VL, O);
}

// Round 15
// 32.290 us; speedup vs baseline: 3.1956x; 1.0220x over previous
//
#include <hip/hip_runtime.h>
#include <hip/hip_bf16.h>

// R26 = R25/R21 (verified champion, 33.0us) + ONE change: defer-max vote moved
// BEFORE the cross-lane reduce, voting on the LANE-LOCAL max.
// Equivalence: m_run is row-uniform, and max(group) <= thr  <=>  all members
// <= thr, so __all(tm_lane <= m_run+THR) == __all(tm_row <= m_run+THR) --
// identical vote outcome, bit-identical output. Effect: the two dependent
// __shfl_xor (ds_permute, ~100-200cyc round trip) leave the critical path on
// SKIP tiles -- which defer-max (THR=8) makes the ~90% case. They run only on
// !skip (tile 0 + rare max spikes), where the full R21 sequence is preserved.
// Everything else R25-verbatim: 8 waves x 16 q-rows, ONE barrier/tile,
// unroll-2 literal bs, hoisted off8, prow-permuted K, in-register P, swz16
// V^T b128 reads, stratified-LPT + XCD clustering + pairing perm.
// Ledger: structural probes R17/R18/R19/R24 all regressed; R20/R22/R23 micro
// bundles neutral-negative; R21 (VALU/addr trim) and this (latency trim) are
// the only lever class that has moved the champion.

#define NB    64
#define LQ    1024
#define LK    1024
#define DH    64
#define KVT   64
#define QT    128
#define NITEMS (NB * (LQ / QT))      // 512
#define NEGF  1.0e30f
#define SC2   0.18033688011112042f   // 0.125 * log2(e)
#define THR   8.0f                   // defer-max threshold (log2 units)

typedef __attribute__((ext_vector_type(8))) short    bf8;
typedef __attribute__((ext_vector_type(8))) ushort   u16x8;
typedef __attribute__((ext_vector_type(4))) ushort   u16x4;
typedef __attribute__((ext_vector_type(4))) float    f4;

__device__ __forceinline__ ushort2 cvt2(float a, float b) {   // v_cvt_pk_bf16_f32
    float2 f; f.x = a; f.y = b;
    __hip_bfloat162 h = __float22bfloat162_rn(f);
    union { __hip_bfloat162 h2; ushort2 u2; } u;
    u.h2 = h;
    return u.u2;
}
__device__ __forceinline__ int swz16(int row, int colbyte) {  // K, V^T tiles
    return row * 128 + ((((colbyte >> 4) ^ (row & 7)) << 4) | (colbyte & 15));
}
__device__ __forceinline__ float fm3(float a, float b, float c) {  // v_max3
    return fmaxf(fmaxf(a, b), c);
}

__global__ __launch_bounds__(512, 4)
void attn_v26(const float* __restrict__ Q, const float* __restrict__ K,
              const float* __restrict__ V, const int* __restrict__ VL,
              float* __restrict__ O) {
    __shared__ ushort KsB[2][KVT * DH];   // swz16 [phys key][d] 16 KB
    __shared__ ushort VtB[2][DH * KVT];   // swz16 [d][key]      16 KB
    __shared__ ushort sched[NB];          // rank -> batch        128 B => 32896

    const int tid = threadIdx.x;
    const int wid = tid >> 6, l = tid & 63, g = l >> 4, a = l & 15;

    // ---- in-kernel stratified-LPT schedule ----
    if (tid < NB) {
        const int ntb = (VL[tid] + KVT - 1) >> 6;
        int r = 0;
        for (int j = 0; j < NB; ++j) {
            const int ntj = (VL[j] + KVT - 1) >> 6;
            r += (int)((ntj > ntb) | ((ntj == ntb) & (j < tid)));
        }
        sched[r] = (ushort)tid;           // rank -> batch (desc nt, tie asc)
    }
    __syncthreads();
    const int xcd   = blockIdx.x & 7;     // HW: block i -> XCD i%8
    const int slot  = blockIdx.x >> 3;    // 0..63 within XCD
    const int qtile = slot & 7;           // 8 q-slots of 128 rows
    const int st    = slot >> 3;          // stratum 0..7
    // pairing perm8={0,1,2,3,7,6,5,4}: CU gets complementary strata
    const int rank  = xcd + ((st < 4) ? st : (11 - st)) * 8;
    const int b     = sched[rank];
    const int qbase = qtile * QT;
    const int valid = VL[b];              // 1..1024
    const int nt = (valid + KVT - 1) >> 6;

    // Hoisted LDS read offsets: same formula serves K and V reads.
    int off8[8];                          // [n][kblk] -> n*2 + kblk
    #pragma unroll
    for (int n = 0; n < 4; ++n)
        #pragma unroll
        for (int kblk = 0; kblk < 2; ++kblk)
            off8[n * 2 + kblk] = swz16(n * 16 + a, kblk * 64 + g * 16);

    // Q fragment (B-operand), pre-scaled by SC2: col=a (q-row), k=32kblk+8g+i
    const float* Qr = Q + ((size_t)b * LQ + qbase + wid * 16 + a) * DH;
    bf8 qa[2];
    #pragma unroll
    for (int kblk = 0; kblk < 2; ++kblk) {
        f4 x = *(const f4*)(Qr + kblk * 32 + g * 8);
        f4 y = *(const f4*)(Qr + kblk * 32 + g * 8 + 4);
        ushort2 c0 = cvt2(x[0] * SC2, x[1] * SC2), c1 = cvt2(x[2] * SC2, x[3] * SC2);
        ushort2 c2 = cvt2(y[0] * SC2, y[1] * SC2), c3 = cvt2(y[2] * SC2, y[3] * SC2);
        qa[kblk][0] = (short)c0.x; qa[kblk][1] = (short)c0.y;
        qa[kblk][2] = (short)c1.x; qa[kblk][3] = (short)c1.y;
        qa[kblk][4] = (short)c2.x; qa[kblk][5] = (short)c2.y;
        qa[kblk][6] = (short)c3.x; qa[kblk][7] = (short)c3.y;
    }
    const bf8 ones = {0x3F80, 0x3F80, 0x3F80, 0x3F80,
                      0x3F80, 0x3F80, 0x3F80, 0x3F80};   // bf16 1.0 x8

    // staging roles: waves 0-3 stage V, waves 4-7 stage K (R16 split)
    const int  rtid  = tid & 255;
    const bool vrole = (wid < 4);
    const int srow = rtid >> 3, sslot = rtid & 7;   // K rows srow, srow+32
    const int vkp  = rtid >> 4, vj = rtid & 15;     // V keys 4vkp.., f4-col vj
    // physical LDS row for K key srow (<32): swap bits 3..4 with bit 2
    const int prow = (srow & 3) | ((srow & 24) >> 1) | ((srow & 4) << 2);
    const f4* Kb4 = (const f4*)(K + (size_t)b * LK * DH);
    const f4* Vb4 = (const f4*)(V + (size_t)b * LK * DH);

    f4 r0, r1, r2, r3;
    auto load_kv = [&](int k0) {
        if (vrole) {
            r0 = Vb4[(k0 + 4 * vkp + 0) * 16 + vj];
            r1 = Vb4[(k0 + 4 * vkp + 1) * 16 + vj];
            r2 = Vb4[(k0 + 4 * vkp + 2) * 16 + vj];
            r3 = Vb4[(k0 + 4 * vkp + 3) * 16 + vj];
        } else {
            r0 = Kb4[(k0 + srow) * 16 + sslot * 2];
            r1 = Kb4[(k0 + srow) * 16 + sslot * 2 + 1];
            r2 = Kb4[(k0 + srow + 32) * 16 + sslot * 2];
            r3 = Kb4[(k0 + srow + 32) * 16 + sslot * 2 + 1];
        }
    };
    auto store_kv = [&](int bs) {
        if (vrole) {
            char* vd = (char*)&VtB[bs][0];
            #pragma unroll
            for (int c = 0; c < 4; ++c) {      // transpose: d = 4*vj+c
                ushort2 a01 = cvt2(r0[c], r1[c]), a23 = cvt2(r2[c], r3[c]);
                u16x4 p = {a01.x, a01.y, a23.x, a23.y};
                *(u16x4*)(vd + swz16(4 * vj + c, vkp * 8)) = p;
            }
        } else {
            char* kd = (char*)&KsB[bs][0];
            {
                ushort2 c0 = cvt2(r0[0], r0[1]), c1 = cvt2(r0[2], r0[3]);
                ushort2 c2 = cvt2(r1[0], r1[1]), c3 = cvt2(r1[2], r1[3]);
                u16x8 w = {c0.x, c0.y, c1.x, c1.y, c2.x, c2.y, c3.x, c3.y};
                *(u16x8*)(kd + swz16(prow, sslot * 16)) = w;
            }
            {
                ushort2 c0 = cvt2(r2[0], r2[1]), c1 = cvt2(r2[2], r2[3]);
                ushort2 c2 = cvt2(r3[0], r3[1]), c3 = cvt2(r3[2], r3[3]);
                u16x8 w = {c0.x, c0.y, c1.x, c1.y, c2.x, c2.y, c3.x, c3.y};
                *(u16x8*)(kd + swz16(prow + 32, sslot * 16)) = w;
            }
        }
    };

    f4 oacc[4];
    #pragma unroll
    for (int n = 0; n < 4; ++n) oacc[n] = f4{0.f, 0.f, 0.f, 0.f};
    f4 lacc = f4{0.f, 0.f, 0.f, 0.f};   // l per q-row 4g+r (epilogue layout)
    float m_run = -NEGF;                // per-lane: q-row = a (row-uniform)

    // One tile iteration; bs is a LITERAL at every callsite so the LDS base
    // folds into ds_read/ds_write immediates.
    auto tile_iter = [&](int t, const int bs) {
        __syncthreads();                         // buf[bs] ready block-wide
        if (t + 1 < nt) load_kv((t + 1) * KVT);  // issue early...
        __builtin_amdgcn_sched_barrier(0);       // ...keep it early

        // ---- S^T = K Q^T: lane (g,a) holds S[q=a][key=32(n>>1)+4(n&1)+8g+r]
        const char* kd = (const char*)&KsB[bs][0];
        f4 sacc[4];
        #pragma unroll
        for (int n = 0; n < 4; ++n) sacc[n] = f4{0.f, 0.f, 0.f, 0.f};
        __builtin_amdgcn_s_setprio(1);
        #pragma unroll
        for (int n = 0; n < 4; ++n)
            #pragma unroll
            for (int kblk = 0; kblk < 2; ++kblk) {
                bf8 kb = *(const bf8*)(kd + off8[n * 2 + kblk]);
                sacc[n] = __builtin_amdgcn_mfma_f32_16x16x32_bf16(
                    kb, qa[kblk], sacc[n], 0, 0, 0);   // A=K, B=Q
            }
        __builtin_amdgcn_s_setprio(0);

        // ---- mask in place ----
        const int kmax = valid - t * KVT;
        if (kmax < KVT) {
            #pragma unroll
            for (int n = 0; n < 4; ++n)
                #pragma unroll
                for (int r = 0; r < 4; ++r)
                    if (32 * (n >> 1) + 4 * (n & 1) + 8 * g + r >= kmax)
                        sacc[n][r] = -NEGF;
        }

        // ---- lane-local max: 3-ary tree (v_max3), NO cross-lane yet ----
        float t0 = fm3(sacc[0][0], sacc[0][1], sacc[0][2]);
        float t1 = fm3(sacc[0][3], sacc[1][0], sacc[1][1]);
        float t2 = fm3(sacc[1][2], sacc[1][3], sacc[2][0]);
        float t3 = fm3(sacc[2][1], sacc[2][2], sacc[2][3]);
        float t4 = fm3(sacc[3][0], sacc[3][1], sacc[3][2]);
        float tm = fm3(fm3(t0, t1, t2), fm3(t3, t4, sacc[3][3]),
                       -NEGF);

        // ---- defer-max vote on LANE-LOCAL max (== row-max vote: m_run is
        //      row-uniform, and max(group)<=thr <=> all members<=thr).
        //      Shuffles + rescale only on the rare !skip path. ----
        const bool skip = __all(tm <= m_run + THR);
        if (!skip) {
            tm = fmaxf(tm, __shfl_xor(tm, 16));   // row max (as R21)
            tm = fmaxf(tm, __shfl_xor(tm, 32));
            const float mnew = fmaxf(m_run, tm);
            const float rs_ = __builtin_exp2f(m_run - mnew);  // tile0: 0
            m_run = mnew;
            float rr[4];
            #pragma unroll
            for (int r = 0; r < 4; ++r) rr[r] = __shfl(rs_, 4 * g + r);
            #pragma unroll
            for (int n = 0; n < 4; ++n)
                #pragma unroll
                for (int r = 0; r < 4; ++r) oacc[n][r] *= rr[r];
            #pragma unroll
            for (int r = 0; r < 4; ++r) lacc[r] *= rr[r];
        }

        float p[4][4];
        #pragma unroll
        for (int n = 0; n < 4; ++n)
            #pragma unroll
            for (int r = 0; r < 4; ++r)
                p[n][r] = __builtin_exp2f(sacc[n][r] - m_run);   // masked -> 0

        // ---- O += P V ; l += P * ones  (P in registers; vb one b128) ----
        const char* vd = (const char*)&VtB[bs][0];
        __builtin_amdgcn_s_setprio(1);
        #pragma unroll
        for (int kblk = 0; kblk < 2; ++kblk) {
            ushort2 w0 = cvt2(p[2 * kblk][0], p[2 * kblk][1]);
            ushort2 w1 = cvt2(p[2 * kblk][2], p[2 * kblk][3]);
            ushort2 w2 = cvt2(p[2 * kblk + 1][0], p[2 * kblk + 1][1]);
            ushort2 w3 = cvt2(p[2 * kblk + 1][2], p[2 * kblk + 1][3]);
            bf8 pa = {(short)w0.x, (short)w0.y, (short)w1.x, (short)w1.y,
                      (short)w2.x, (short)w2.y, (short)w3.x, (short)w3.y};
            #pragma unroll
            for (int n = 0; n < 4; ++n) {
                bf8 vb_ = *(const bf8*)(vd + off8[n * 2 + kblk]);
                oacc[n] = __builtin_amdgcn_mfma_f32_16x16x32_bf16(
                    pa, vb_, oacc[n], 0, 0, 0);
            }
            lacc = __builtin_amdgcn_mfma_f32_16x16x32_bf16(pa, ones, lacc, 0, 0, 0);
        }
        __builtin_amdgcn_s_setprio(0);

        if (t + 1 < nt) store_kv(bs ^ 1);   // post-compute, pre-next-barrier
    };

    load_kv(0);
    store_kv(0);
    for (int t = 0; t < nt; t += 2) {       // unroll-2: bs literal
        tile_iter(t, 0);
        if (t + 1 < nt) tile_iter(t + 1, 1);
    }

    // ---- epilogue: O[q=4g+r][d=16n+a] / l (lacc already row-layout) ----
    float iv[4];
    #pragma unroll
    for (int r = 0; r < 4; ++r) iv[r] = 1.0f / lacc[r];
    float* Ob = O + ((size_t)b * LQ + qbase + wid * 16) * DH;
    #pragma unroll
    for (int n = 0; n < 4; ++n)
        #pragma unroll
        for (int r = 0; r < 4; ++r)
            Ob[(size_t)(4 * g + r) * DH + 16 * n + a] = oacc[n][r] * iv[r];
}

extern "C" void kernel_launch(void* const* d_in, const int* in_sizes, int n_in,
                              void* d_out, int out_size, void* d_ws, size_t ws_size,
                              hipStream_t stream) {
    const float* Q  = (const float*)d_in[0];
    const float* K  = (const float*)d_in[1];
    const float* V  = (const float*)d_in[2];
    const int*   VL = (const int*)d_in[3];
    float* O = (float*)d_out;

    attn_v26<<<NITEMS, 512, 0, stream>>>(Q, K, V, VL, O);
}

// Round 16
// 31.429 us; speedup vs baseline: 3.2831x; 1.0274x over previous
//
#include <hip/hip_runtime.h>
#include <hip/hip_bf16.h>

// R27 = R26 (verified champion, 32.29us) + 4-buffer LDS / one barrier per TWO
// tiles. The last fixed per-tile cost in the common path is the s_barrier
// (compiler-emitted vmcnt(0)/lgkmcnt(0) drain + 8-wave skew, ~100-200cyc).
// R18 failed by ADDING barriers; this is the inverse: with 4 K/V buffer pairs
// (64KB LDS, still 2 blocks/CU -- grid-capped anyway) one barrier fences a
// tile PAIR. Race analysis (nt block-uniform -> all guards uniform, barriers
// converged): pair (t,t+1) reads bufs {t%4,(t+1)%4}; mid-pair stores hit bufs
// {(t+2)%4,(t+3)%4} whose last readers (tiles t-2,t-1) all finished before
// the pair-top barrier; next pair's barrier drains the ds_writes before any
// read. Per-tile load/store cadence unchanged (1 load + 1 store, >=1 tile of
// cover, single staging reg set). Unroll-4 keeps buf indices literal.
// Compute body R26-verbatim (lane-local defer-max vote, hoisted off8, prow-
// permuted K, in-register P, swz16 V^T b128 reads) -> output bit-identical.
// Ledger: chain-trim lever class is the only one that moves this kernel
// (R21 +0.5, R26 +0.7); structural probes R17/R18/R19/R24 all regressed.

#define NB    64
#define LQ    1024
#define LK    1024
#define DH    64
#define KVT   64
#define QT    128
#define NITEMS (NB * (LQ / QT))      // 512
#define NEGF  1.0e30f
#define SC2   0.18033688011112042f   // 0.125 * log2(e)
#define THR   8.0f                   // defer-max threshold (log2 units)

typedef __attribute__((ext_vector_type(8))) short    bf8;
typedef __attribute__((ext_vector_type(8))) ushort   u16x8;
typedef __attribute__((ext_vector_type(4))) ushort   u16x4;
typedef __attribute__((ext_vector_type(4))) float    f4;

__device__ __forceinline__ ushort2 cvt2(float a, float b) {   // v_cvt_pk_bf16_f32
    float2 f; f.x = a; f.y = b;
    __hip_bfloat162 h = __float22bfloat162_rn(f);
    union { __hip_bfloat162 h2; ushort2 u2; } u;
    u.h2 = h;
    return u.u2;
}
__device__ __forceinline__ int swz16(int row, int colbyte) {  // K, V^T tiles
    return row * 128 + ((((colbyte >> 4) ^ (row & 7)) << 4) | (colbyte & 15));
}
__device__ __forceinline__ float fm3(float a, float b, float c) {  // v_max3
    return fmaxf(fmaxf(a, b), c);
}

__global__ __launch_bounds__(512, 4)
void attn_v27(const float* __restrict__ Q, const float* __restrict__ K,
              const float* __restrict__ V, const int* __restrict__ VL,
              float* __restrict__ O) {
    __shared__ ushort KsB[4][KVT * DH];   // swz16 [phys key][d] 32 KB
    __shared__ ushort VtB[4][DH * KVT];   // swz16 [d][key]      32 KB
    __shared__ ushort sched[NB];          // rank -> batch        128 B => 65664

    const int tid = threadIdx.x;
    const int wid = tid >> 6, l = tid & 63, g = l >> 4, a = l & 15;

    // ---- in-kernel stratified-LPT schedule ----
    if (tid < NB) {
        const int ntb = (VL[tid] + KVT - 1) >> 6;
        int r = 0;
        for (int j = 0; j < NB; ++j) {
            const int ntj = (VL[j] + KVT - 1) >> 6;
            r += (int)((ntj > ntb) | ((ntj == ntb) & (j < tid)));
        }
        sched[r] = (ushort)tid;           // rank -> batch (desc nt, tie asc)
    }
    __syncthreads();
    const int xcd   = blockIdx.x & 7;     // HW: block i -> XCD i%8
    const int slot  = blockIdx.x >> 3;    // 0..63 within XCD
    const int qtile = slot & 7;           // 8 q-slots of 128 rows
    const int st    = slot >> 3;          // stratum 0..7
    // pairing perm8={0,1,2,3,7,6,5,4}: CU gets complementary strata
    const int rank  = xcd + ((st < 4) ? st : (11 - st)) * 8;
    const int b     = sched[rank];
    const int qbase = qtile * QT;
    const int valid = VL[b];              // 1..1024
    const int nt = (valid + KVT - 1) >> 6;

    // Hoisted LDS read offsets: same formula serves K and V reads.
    int off8[8];                          // [n][kblk] -> n*2 + kblk
    #pragma unroll
    for (int n = 0; n < 4; ++n)
        #pragma unroll
        for (int kblk = 0; kblk < 2; ++kblk)
            off8[n * 2 + kblk] = swz16(n * 16 + a, kblk * 64 + g * 16);

    // Q fragment (B-operand), pre-scaled by SC2: col=a (q-row), k=32kblk+8g+i
    const float* Qr = Q + ((size_t)b * LQ + qbase + wid * 16 + a) * DH;
    bf8 qa[2];
    #pragma unroll
    for (int kblk = 0; kblk < 2; ++kblk) {
        f4 x = *(const f4*)(Qr + kblk * 32 + g * 8);
        f4 y = *(const f4*)(Qr + kblk * 32 + g * 8 + 4);
        ushort2 c0 = cvt2(x[0] * SC2, x[1] * SC2), c1 = cvt2(x[2] * SC2, x[3] * SC2);
        ushort2 c2 = cvt2(y[0] * SC2, y[1] * SC2), c3 = cvt2(y[2] * SC2, y[3] * SC2);
        qa[kblk][0] = (short)c0.x; qa[kblk][1] = (short)c0.y;
        qa[kblk][2] = (short)c1.x; qa[kblk][3] = (short)c1.y;
        qa[kblk][4] = (short)c2.x; qa[kblk][5] = (short)c2.y;
        qa[kblk][6] = (short)c3.x; qa[kblk][7] = (short)c3.y;
    }
    const bf8 ones = {0x3F80, 0x3F80, 0x3F80, 0x3F80,
                      0x3F80, 0x3F80, 0x3F80, 0x3F80};   // bf16 1.0 x8

    // staging roles: waves 0-3 stage V, waves 4-7 stage K (R16 split)
    const int  rtid  = tid & 255;
    const bool vrole = (wid < 4);
    const int srow = rtid >> 3, sslot = rtid & 7;   // K rows srow, srow+32
    const int vkp  = rtid >> 4, vj = rtid & 15;     // V keys 4vkp.., f4-col vj
    // physical LDS row for K key srow (<32): swap bits 3..4 with bit 2
    const int prow = (srow & 3) | ((srow & 24) >> 1) | ((srow & 4) << 2);
    const f4* Kb4 = (const f4*)(K + (size_t)b * LK * DH);
    const f4* Vb4 = (const f4*)(V + (size_t)b * LK * DH);

    f4 r0, r1, r2, r3;
    auto load_kv = [&](int k0) {
        if (vrole) {
            r0 = Vb4[(k0 + 4 * vkp + 0) * 16 + vj];
            r1 = Vb4[(k0 + 4 * vkp + 1) * 16 + vj];
            r2 = Vb4[(k0 + 4 * vkp + 2) * 16 + vj];
            r3 = Vb4[(k0 + 4 * vkp + 3) * 16 + vj];
        } else {
            r0 = Kb4[(k0 + srow) * 16 + sslot * 2];
            r1 = Kb4[(k0 + srow) * 16 + sslot * 2 + 1];
            r2 = Kb4[(k0 + srow + 32) * 16 + sslot * 2];
            r3 = Kb4[(k0 + srow + 32) * 16 + sslot * 2 + 1];
        }
    };
    auto store_kv = [&](const int bs) {
        if (vrole) {
            char* vd = (char*)&VtB[bs][0];
            #pragma unroll
            for (int c = 0; c < 4; ++c) {      // transpose: d = 4*vj+c
                ushort2 a01 = cvt2(r0[c], r1[c]), a23 = cvt2(r2[c], r3[c]);
                u16x4 p = {a01.x, a01.y, a23.x, a23.y};
                *(u16x4*)(vd + swz16(4 * vj + c, vkp * 8)) = p;
            }
        } else {
            char* kd = (char*)&KsB[bs][0];
            {
                ushort2 c0 = cvt2(r0[0], r0[1]), c1 = cvt2(r0[2], r0[3]);
                ushort2 c2 = cvt2(r1[0], r1[1]), c3 = cvt2(r1[2], r1[3]);
                u16x8 w = {c0.x, c0.y, c1.x, c1.y, c2.x, c2.y, c3.x, c3.y};
                *(u16x8*)(kd + swz16(prow, sslot * 16)) = w;
            }
            {
                ushort2 c0 = cvt2(r2[0], r2[1]), c1 = cvt2(r2[2], r2[3]);
                ushort2 c2 = cvt2(r3[0], r3[1]), c3 = cvt2(r3[2], r3[3]);
                u16x8 w = {c0.x, c0.y, c1.x, c1.y, c2.x, c2.y, c3.x, c3.y};
                *(u16x8*)(kd + swz16(prow + 32, sslot * 16)) = w;
            }
        }
    };

    f4 oacc[4];
    #pragma unroll
    for (int n = 0; n < 4; ++n) oacc[n] = f4{0.f, 0.f, 0.f, 0.f};
    f4 lacc = f4{0.f, 0.f, 0.f, 0.f};   // l per q-row 4g+r (epilogue layout)
    float m_run = -NEGF;                // per-lane: q-row = a (row-uniform)

    // Pure compute for one tile; bs literal -> LDS bases fold into ds imms.
    auto compute_tile = [&](int t, const int bs) {
        // ---- S^T = K Q^T: lane (g,a) holds S[q=a][key=32(n>>1)+4(n&1)+8g+r]
        const char* kd = (const char*)&KsB[bs][0];
        f4 sacc[4];
        #pragma unroll
        for (int n = 0; n < 4; ++n) sacc[n] = f4{0.f, 0.f, 0.f, 0.f};
        __builtin_amdgcn_s_setprio(1);
        #pragma unroll
        for (int n = 0; n < 4; ++n)
            #pragma unroll
            for (int kblk = 0; kblk < 2; ++kblk) {
                bf8 kb = *(const bf8*)(kd + off8[n * 2 + kblk]);
                sacc[n] = __builtin_amdgcn_mfma_f32_16x16x32_bf16(
                    kb, qa[kblk], sacc[n], 0, 0, 0);   // A=K, B=Q
            }
        __builtin_amdgcn_s_setprio(0);

        // ---- mask in place ----
        const int kmax = valid - t * KVT;
        if (kmax < KVT) {
            #pragma unroll
            for (int n = 0; n < 4; ++n)
                #pragma unroll
                for (int r = 0; r < 4; ++r)
                    if (32 * (n >> 1) + 4 * (n & 1) + 8 * g + r >= kmax)
                        sacc[n][r] = -NEGF;
        }

        // ---- lane-local max: 3-ary tree (v_max3), no cross-lane ----
        float t0 = fm3(sacc[0][0], sacc[0][1], sacc[0][2]);
        float t1 = fm3(sacc[0][3], sacc[1][0], sacc[1][1]);
        float t2 = fm3(sacc[1][2], sacc[1][3], sacc[2][0]);
        float t3 = fm3(sacc[2][1], sacc[2][2], sacc[2][3]);
        float t4 = fm3(sacc[3][0], sacc[3][1], sacc[3][2]);
        float tm = fm3(fm3(t0, t1, t2), fm3(t3, t4, sacc[3][3]),
                       -NEGF);

        // ---- defer-max vote on lane-local max (== row-max vote) ----
        const bool skip = __all(tm <= m_run + THR);
        if (!skip) {
            tm = fmaxf(tm, __shfl_xor(tm, 16));   // row max (rare path)
            tm = fmaxf(tm, __shfl_xor(tm, 32));
            const float mnew = fmaxf(m_run, tm);
            const float rs_ = __builtin_exp2f(m_run - mnew);  // tile0: 0
            m_run = mnew;
            float rr[4];
            #pragma unroll
            for (int r = 0; r < 4; ++r) rr[r] = __shfl(rs_, 4 * g + r);
            #pragma unroll
            for (int n = 0; n < 4; ++n)
                #pragma unroll
                for (int r = 0; r < 4; ++r) oacc[n][r] *= rr[r];
            #pragma unroll
            for (int r = 0; r < 4; ++r) lacc[r] *= rr[r];
        }

        float p[4][4];
        #pragma unroll
        for (int n = 0; n < 4; ++n)
            #pragma unroll
            for (int r = 0; r < 4; ++r)
                p[n][r] = __builtin_exp2f(sacc[n][r] - m_run);   // masked -> 0

        // ---- O += P V ; l += P * ones  (P in registers; vb one b128) ----
        const char* vd = (const char*)&VtB[bs][0];
        __builtin_amdgcn_s_setprio(1);
        #pragma unroll
        for (int kblk = 0; kblk < 2; ++kblk) {
            ushort2 w0 = cvt2(p[2 * kblk][0], p[2 * kblk][1]);
            ushort2 w1 = cvt2(p[2 * kblk][2], p[2 * kblk][3]);
            ushort2 w2 = cvt2(p[2 * kblk + 1][0], p[2 * kblk + 1][1]);
            ushort2 w3 = cvt2(p[2 * kblk + 1][2], p[2 * kblk + 1][3]);
            bf8 pa = {(short)w0.x, (short)w0.y, (short)w1.x, (short)w1.y,
                      (short)w2.x, (short)w2.y, (short)w3.x, (short)w3.y};
            #pragma unroll
            for (int n = 0; n < 4; ++n) {
                bf8 vb_ = *(const bf8*)(vd + off8[n * 2 + kblk]);
                oacc[n] = __builtin_amdgcn_mfma_f32_16x16x32_bf16(
                    pa, vb_, oacc[n], 0, 0, 0);
            }
            lacc = __builtin_amdgcn_mfma_f32_16x16x32_bf16(pa, ones, lacc, 0, 0, 0);
        }
        __builtin_amdgcn_s_setprio(0);
    };

    // ---- prologue: stage tiles 0,1 into bufs 0,1 ----
    load_kv(0);
    store_kv(0);
    if (nt > 1) { load_kv(KVT); store_kv(1); }

    // ---- main loop: ONE barrier per tile PAIR; bufs cycle 0,1,2,3 ----
    for (int t = 0; t < nt; t += 4) {
        __syncthreads();                       // bufs {0,1} ready; {2,3} free
        if (t + 2 < nt) load_kv((t + 2) * KVT);
        __builtin_amdgcn_sched_barrier(0);
        compute_tile(t, 0);
        if (t + 2 < nt) store_kv(2);
        if (t + 3 < nt) load_kv((t + 3) * KVT);
        __builtin_amdgcn_sched_barrier(0);
        if (t + 1 < nt) compute_tile(t + 1, 1);
        if (t + 3 < nt) store_kv(3);
        if (t + 2 < nt) {
            __syncthreads();                   // bufs {2,3} ready; {0,1} free
            if (t + 4 < nt) load_kv((t + 4) * KVT);
            __builtin_amdgcn_sched_barrier(0);
            compute_tile(t + 2, 2);
            if (t + 4 < nt) store_kv(0);
            if (t + 5 < nt) load_kv((t + 5) * KVT);
            __builtin_amdgcn_sched_barrier(0);
            if (t + 3 < nt) compute_tile(t + 3, 3);
            if (t + 5 < nt) store_kv(1);
        }
    }

    // ---- epilogue: O[q=4g+r][d=16n+a] / l (lacc already row-layout) ----
    float iv[4];
    #pragma unroll
    for (int r = 0; r < 4; ++r) iv[r] = 1.0f / lacc[r];
    float* Ob = O + ((size_t)b * LQ + qbase + wid * 16) * DH;
    #pragma unroll
    for (int n = 0; n < 4; ++n)
        #pragma unroll
        for (int r = 0; r < 4; ++r)
            Ob[(size_t)(4 * g + r) * DH + 16 * n + a] = oacc[n][r] * iv[r];
}

extern "C" void kernel_launch(void* const* d_in, const int* in_sizes, int n_in,
                              void* d_out, int out_size, void* d_ws, size_t ws_size,
                              hipStream_t stream) {
    const float* Q  = (const float*)d_in[0];
    const float* K  = (const float*)d_in[1];
    const float* V  = (const float*)d_in[2];
    const int*   VL = (const int*)d_in[3];
    float* O = (float*)d_out;

    attn_v27<<<NITEMS, 512, 0, stream>>>(Q, K, V, VL, O);
}